// Round 15
// baseline (412.047 us; speedup 1.0000x reference)
//
#include <hip/hip_runtime.h>
#include <cstdint>

typedef unsigned long long u64;
typedef unsigned int u32;

#define DIM    10000
#define NCLS   100
#define BATCH  4096
#define F4ROW  2500          // float4s per input row
#define NCH    40            // 256-dim chunks per row (chunk 39 partial)
#define REPS   5             // probe passes over q (for top-5 visibility)
#define N4     ((size_t)BATCH * DIM / 4)   // 10,240,000 float4s (64-divisible)

// ============ PROBES: grid-stride 2048x256, REPS passes, rep-shifted ============

// B: stream + ballot (isolates ballot cost vs probe A's 23.3 us/pass)
__global__ __launch_bounds__(256) void probe_ballot(const float* __restrict__ in,
                                                    u64* __restrict__ sink) {
    const size_t stride = (size_t)gridDim.x * 256;
    u64 acc = 0;
    for (int rep = 0; rep < REPS; ++rep) {
        const size_t off = (size_t)rep * 64;
        for (size_t i = (size_t)blockIdx.x * 256 + threadIdx.x; i < N4; i += stride) {
            size_t ii = i + off; if (ii >= N4) ii -= N4;      // distinct addrs/rep
            const float4 v = *(const float4*)(in + ii * 4);
            acc += __ballot(v.x > 0.5f);
            acc += __ballot(v.y > 0.5f);
            acc += __ballot(v.z > 0.5f);
            acc += __ballot(v.w > 0.5f);
        }
    }
    if (acc == 0x123456789ABCDEF0ull) sink[threadIdx.x] = acc;   // keep loads live
}

// C: + xor/popcount consume matched to fused_v4 (8 popcll/chunk, VGPR operands)
__global__ __launch_bounds__(256) void probe_popc(const float* __restrict__ in,
                                                  u64* __restrict__ sink) {
    const size_t stride = (size_t)gridDim.x * 256;
    const u64 c0 = 0x9E3779B97F4A7C15ull * (u64)(threadIdx.x + 1);
    const u64 c1 = 0xC2B2AE3D27D4EB4Full * (u64)(threadIdx.x + 7);
    u32 acc = 0;
    for (int rep = 0; rep < REPS; ++rep) {
        const size_t off = (size_t)rep * 64;
        for (size_t i = (size_t)blockIdx.x * 256 + threadIdx.x; i < N4; i += stride) {
            size_t ii = i + off; if (ii >= N4) ii -= N4;
            const float4 v = *(const float4*)(in + ii * 4);
            const u64 b0 = __ballot(v.x > 0.5f);
            const u64 b1 = __ballot(v.y > 0.5f);
            const u64 b2 = __ballot(v.z > 0.5f);
            const u64 b3 = __ballot(v.w > 0.5f);
            acc += (u32)(__popcll(b0 ^ c0) + __popcll(b1 ^ c0) +
                         __popcll(b2 ^ c1) + __popcll(b3 ^ c1));
            acc += (u32)(__popcll(b0 ^ c1) + __popcll(b1 ^ c1) +
                         __popcll(b2 ^ c0) + __popcll(b3 ^ c0));
        }
    }
    if (acc == 0xDEADBEEFu) sink[threadIdx.x] = (u64)acc;
}

// D: + real apT2 loads (fused_v4's exact per-chunk ap pattern, wave-uniform c)
__global__ __launch_bounds__(256) void probe_ap(const float* __restrict__ in,
                                                const ulonglong2* __restrict__ apT2,
                                                u64* __restrict__ sink) {
    const size_t stride = (size_t)gridDim.x * 256;
    const int lane = threadIdx.x & 63;
    const int clsA = lane;
    const int clsB = 64 + (lane < NCLS - 64 ? lane : NCLS - 65);
    u32 acc = 0;
    for (int rep = 0; rep < REPS; ++rep) {
        const size_t off = (size_t)rep * 64;
        for (size_t i = (size_t)blockIdx.x * 256 + threadIdx.x; i < N4; i += stride) {
            size_t ii = i + off; if (ii >= N4) ii -= N4;      // N4%64==0: ii>>6 uniform
            const float4 v = *(const float4*)(in + ii * 4);
            const int c = (int)((ii >> 6) % NCH);             // wave-uniform chunk
            const ulonglong2* wp0 = apT2 + (size_t)(2 * c) * NCLS;
            const ulonglong2* wp1 = wp0 + NCLS;
            const ulonglong2 aA0 = wp0[clsA];
            const ulonglong2 aA1 = wp1[clsA];
            const ulonglong2 aB0 = wp0[clsB];
            const ulonglong2 aB1 = wp1[clsB];
            const u64 b0 = __ballot(v.x > 0.5f);
            const u64 b1 = __ballot(v.y > 0.5f);
            const u64 b2 = __ballot(v.z > 0.5f);
            const u64 b3 = __ballot(v.w > 0.5f);
            acc += (u32)(__popcll(b0 ^ aA0.x) + __popcll(b1 ^ aA0.y) +
                         __popcll(b2 ^ aA1.x) + __popcll(b3 ^ aA1.y));
            acc += (u32)(__popcll(b0 ^ aB0.x) + __popcll(b1 ^ aB0.y) +
                         __popcll(b2 ^ aB1.x) + __popcll(b3 ^ aB1.y));
        }
    }
    if (acc == 0xDEADBEEFu) sink[threadIdx.x] = (u64)acc;
}

// ============ real pipeline (VERBATIM round 12) ============

__global__ __launch_bounds__(256) void pack_a_t(const float* __restrict__ a,
                                                ulonglong2* __restrict__ apT2) {
    const int lane = threadIdx.x & 63;
    const int r    = blockIdx.x * 4 + (threadIdx.x >> 6);   // class 0..99
    const float* row = a + (size_t)r * DIM;
    for (int C = 0; C < NCH; ++C) {
        const int d0 = C * 256 + lane * 4;
        float4 v = make_float4(0.f, 0.f, 0.f, 0.f);
        if (d0 < DIM) v = *(const float4*)(row + d0);
        const u64 b0 = __ballot(v.x > 0.5f);
        const u64 b1 = __ballot(v.y > 0.5f);
        const u64 b2 = __ballot(v.z > 0.5f);
        const u64 b3 = __ballot(v.w > 0.5f);
        if (lane < 2) {
            ulonglong2 u;
            u.x = lane ? b2 : b0;
            u.y = lane ? b3 : b1;
            apT2[(size_t)(2 * C + lane) * NCLS + r] = u;    // wpair = 2C+lane
        }
    }
}

__global__ __launch_bounds__(256) void fused_v4(const float* __restrict__ q,
                                                const ulonglong2* __restrict__ apT2,
                                                float* __restrict__ out) {
    __shared__ int part[4][4][128];                         // [wave][row][class]
    const int lane = threadIdx.x & 63;
    const int wv   = threadIdx.x >> 6;                      // 0..3 = chunk group
    const int r0   = blockIdx.x * 4;
    const int clsA = lane;
    const int clsB = 64 + (lane < NCLS - 64 ? lane : NCLS - 65);

    u32 accA[4] = {0, 0, 0, 0};
    u32 accB[4] = {0, 0, 0, 0};

    const int Cbeg = wv * 10;
    const int Cfull = (wv == 3) ? 39 : Cbeg + 10;           // chunk 39 handled apart

    for (int C = Cbeg; C < Cfull; ++C) {
        float4 v[4];
#pragma unroll
        for (int ri = 0; ri < 4; ++ri)
            v[ri] = *(const float4*)(q + (size_t)(r0 + ri) * DIM
                                       + (size_t)(C * 64 + lane) * 4);
        const ulonglong2* wp0 = apT2 + (size_t)(2 * C) * NCLS;
        const ulonglong2* wp1 = wp0 + NCLS;
        const ulonglong2 aA0 = wp0[clsA];
        const ulonglong2 aA1 = wp1[clsA];
        const ulonglong2 aB0 = wp0[clsB];
        const ulonglong2 aB1 = wp1[clsB];
#pragma unroll
        for (int ri = 0; ri < 4; ++ri) {
            const u64 b0 = __ballot(v[ri].x > 0.5f);
            const u64 b1 = __ballot(v[ri].y > 0.5f);
            const u64 b2 = __ballot(v[ri].z > 0.5f);
            const u64 b3 = __ballot(v[ri].w > 0.5f);
            accA[ri] += (u32)(__popcll(b0 ^ aA0.x) + __popcll(b1 ^ aA0.y) +
                              __popcll(b2 ^ aA1.x) + __popcll(b3 ^ aA1.y));
            accB[ri] += (u32)(__popcll(b0 ^ aB0.x) + __popcll(b1 ^ aB0.y) +
                              __popcll(b2 ^ aB1.x) + __popcll(b3 ^ aB1.y));
        }
    }

    if (wv == 3) {                                          // chunk 39: partial
        const int C    = 39;
        const int idx  = C * 64 + lane;
        const int lidx = idx < F4ROW ? idx : F4ROW - 1;
        const bool ok  = idx < F4ROW;
        const ulonglong2* wp0 = apT2 + (size_t)(2 * C) * NCLS;
        const ulonglong2* wp1 = wp0 + NCLS;
        const ulonglong2 aA0 = wp0[clsA];
        const ulonglong2 aA1 = wp1[clsA];
        const ulonglong2 aB0 = wp0[clsB];
        const ulonglong2 aB1 = wp1[clsB];
#pragma unroll
        for (int ri = 0; ri < 4; ++ri) {
            const float4 v = *(const float4*)(q + (size_t)(r0 + ri) * DIM
                                                + (size_t)lidx * 4);
            const u64 b0 = __ballot(ok && (v.x > 0.5f));
            const u64 b1 = __ballot(ok && (v.y > 0.5f));
            const u64 b2 = __ballot(ok && (v.z > 0.5f));
            const u64 b3 = __ballot(ok && (v.w > 0.5f));
            accA[ri] += (u32)(__popcll(b0 ^ aA0.x) + __popcll(b1 ^ aA0.y) +
                              __popcll(b2 ^ aA1.x) + __popcll(b3 ^ aA1.y));
            accB[ri] += (u32)(__popcll(b0 ^ aB0.x) + __popcll(b1 ^ aB0.y) +
                              __popcll(b2 ^ aB1.x) + __popcll(b3 ^ aB1.y));
        }
    }

#pragma unroll
    for (int ri = 0; ri < 4; ++ri) {
        part[wv][ri][lane] = (int)accA[ri];
        if (lane < NCLS - 64) part[wv][ri][64 + lane] = (int)accB[ri];
    }
    __syncthreads();

    const int tid = threadIdx.x;
#pragma unroll
    for (int o = tid; o < 4 * NCLS; o += 256) {
        const int ri  = o / NCLS;
        const int cls = o - ri * NCLS;
        const int s = part[0][ri][cls] + part[1][ri][cls] +
                      part[2][ri][cls] + part[3][ri][cls];
        out[(size_t)(r0 + ri) * NCLS + cls] = (float)(DIM - s);
    }
}

extern "C" void kernel_launch(void* const* d_in, const int* in_sizes, int n_in,
                              void* d_out, int out_size, void* d_ws, size_t ws_size,
                              hipStream_t stream) {
    const float* q = (const float*)d_in[0];   // [4096, 10000] f32 {0,1}
    const float* a = (const float*)d_in[1];   // [100, 10000]  f32 {0,1}
    float* out = (float*)d_out;               // [4096, 100]   f32

    // ws: apT2 (128,000 B) at 0; probe sink (never written in practice) at 1 MiB
    ulonglong2* apT2 = (ulonglong2*)d_ws;
    u64*        sink = (u64*)((char*)d_ws + (1u << 20));

    pack_a_t<<<25, 256, 0, stream>>>(a, apT2);              // first: D reads real data
    probe_ballot<<<2048, 256, 0, stream>>>(q, sink);        // INSTRUMENTATION
    probe_popc  <<<2048, 256, 0, stream>>>(q, sink);        // INSTRUMENTATION
    probe_ap    <<<2048, 256, 0, stream>>>(q, apT2, sink);  // INSTRUMENTATION
    fused_v4<<<BATCH / 4, 256, 0, stream>>>(q, apT2, out);
}

// Round 16
// 54.604 us; speedup vs baseline: 7.5462x; 7.5462x over previous
//
#include <hip/hip_runtime.h>
#include <cstdint>

typedef unsigned long long u64;
typedef unsigned int u32;

#define DIM    10000
#define NCLS   100
#define BATCH  4096
#define F4ROW  2500          // float4s per input row
#define NCH    40            // 256-dim chunks per row (chunk 39 partial)
#define OUTN   (BATCH * NCLS)

// Bit order (identical for q and am): chunk C covers dims [C*256, C*256+256);
// word j of chunk C, bit i <- dim C*256 + 4i + j (ballot lane i, float4 elem j).
// apT2 layout: [wpair = 2C + s][class]; s=0 holds (b0,b1), s=1 holds (b2,b3).
// Pad dims (>= DIM) give 0-bits on BOTH operands -> XOR contributes nothing.

// ---- pack am -> apT2 (VERBATIM rounds 7/10/11/12) ----
__global__ __launch_bounds__(256) void pack_a_t(const float* __restrict__ a,
                                                ulonglong2* __restrict__ apT2) {
    const int lane = threadIdx.x & 63;
    const int r    = blockIdx.x * 4 + (threadIdx.x >> 6);   // class 0..99
    const float* row = a + (size_t)r * DIM;
    for (int C = 0; C < NCH; ++C) {
        const int d0 = C * 256 + lane * 4;
        float4 v = make_float4(0.f, 0.f, 0.f, 0.f);
        if (d0 < DIM) v = *(const float4*)(row + d0);
        const u64 b0 = __ballot(v.x > 0.5f);
        const u64 b1 = __ballot(v.y > 0.5f);
        const u64 b2 = __ballot(v.z > 0.5f);
        const u64 b3 = __ballot(v.w > 0.5f);
        if (lane < 2) {
            ulonglong2 u;
            u.x = lane ? b2 : b0;
            u.y = lane ? b3 : b1;
            apT2[(size_t)(2 * C + lane) * NCLS + r] = u;    // wpair = 2C+lane
        }
    }
}

// one full chunk: 1 q-load + 4 ap-loads + 4 ballots + 8 popcll (probe D's mix)
__device__ __forceinline__ void chunk_step(const float*& p,
                                           const ulonglong2*& wp,
                                           const int clsA, const int clsB,
                                           u32& accA, u32& accB) {
    const float4 v = *(const float4*)p;
    const u64 b0 = __ballot(v.x > 0.5f);
    const u64 b1 = __ballot(v.y > 0.5f);
    const u64 b2 = __ballot(v.z > 0.5f);
    const u64 b3 = __ballot(v.w > 0.5f);
    const ulonglong2 aA0 = wp[clsA];
    const ulonglong2 aA1 = wp[NCLS + clsA];
    const ulonglong2 aB0 = wp[clsB];
    const ulonglong2 aB1 = wp[NCLS + clsB];
    accA += (u32)(__popcll(b0 ^ aA0.x) + __popcll(b1 ^ aA0.y) +
                  __popcll(b2 ^ aA1.x) + __popcll(b3 ^ aA1.y));
    accB += (u32)(__popcll(b0 ^ aB0.x) + __popcll(b1 ^ aB0.y) +
                  __popcll(b2 ^ aB1.x) + __popcll(b3 ^ aB1.y));
    p  += 256;                                              // next chunk
    wp += 2 * NCLS;
}

// ---- fused v6: probe-clone shape. 2048 blocks x 256 (32 waves/CU).
// wave = one row-half (20 chunks). Register acc only; no LDS; no sync.
__global__ __launch_bounds__(256) void fused_v6(const float* __restrict__ q,
                                                const ulonglong2* __restrict__ apT2,
                                                int* __restrict__ partial) {
    const int lane = threadIdx.x & 63;
    const int u    = blockIdx.x * 4 + (threadIdx.x >> 6);   // work unit 0..8191
    const int row  = u >> 1;
    const int half = u & 1;                                 // 0: C 0..19, 1: C 20..39
    const int clsA = lane;
    const int clsB = 64 + (lane < NCLS - 64 ? lane : NCLS - 65);

    const int C0 = half * 20;
    const float*      p  = q + (size_t)row * DIM + C0 * 256 + lane * 4;
    const ulonglong2* wp = apT2 + (size_t)(2 * C0) * NCLS;

    u32 accA = 0, accB = 0;
    if (half == 0) {                                        // wave-uniform branch
#pragma unroll 4
        for (int c = 0; c < 20; ++c)
            chunk_step(p, wp, clsA, clsB, accA, accB);
    } else {
#pragma unroll 4
        for (int c = 0; c < 19; ++c)                        // chunks 20..38 full
            chunk_step(p, wp, clsA, clsB, accA, accB);
        {   // chunk 39: dims 9984..9999 -> lanes 0..3 only
            const int idx  = 39 * 64 + lane;
            const int lidx = idx < F4ROW ? idx : F4ROW - 1;
            const bool ok  = idx < F4ROW;
            const float4 v = *(const float4*)(q + (size_t)row * DIM + (size_t)lidx * 4);
            const u64 b0 = __ballot(ok && (v.x > 0.5f));
            const u64 b1 = __ballot(ok && (v.y > 0.5f));
            const u64 b2 = __ballot(ok && (v.z > 0.5f));
            const u64 b3 = __ballot(ok && (v.w > 0.5f));
            const ulonglong2 aA0 = wp[clsA];                // wp now at wpair 78
            const ulonglong2 aA1 = wp[NCLS + clsA];
            const ulonglong2 aB0 = wp[clsB];
            const ulonglong2 aB1 = wp[NCLS + clsB];
            accA += (u32)(__popcll(b0 ^ aA0.x) + __popcll(b1 ^ aA0.y) +
                          __popcll(b2 ^ aA1.x) + __popcll(b3 ^ aA1.y));
            accB += (u32)(__popcll(b0 ^ aB0.x) + __popcll(b1 ^ aB0.y) +
                          __popcll(b2 ^ aB1.x) + __popcll(b3 ^ aB1.y));
        }
    }

    int* po = partial + (size_t)half * OUTN + (size_t)row * NCLS;
    po[clsA] = (int)accA;                                   // each slot written once
    if (lane < NCLS - 64) po[64 + lane] = (int)accB;
}

// ---- combine: out = DIM - p0 - p1 (exact small ints -> exact float) ----
__global__ __launch_bounds__(256) void combine_v6(const int* __restrict__ partial,
                                                  float* __restrict__ out) {
    const int i = blockIdx.x * 256 + threadIdx.x;
    out[i] = (float)(DIM - partial[i] - partial[i + OUTN]);
}

extern "C" void kernel_launch(void* const* d_in, const int* in_sizes, int n_in,
                              void* d_out, int out_size, void* d_ws, size_t ws_size,
                              hipStream_t stream) {
    const float* q = (const float*)d_in[0];   // [4096, 10000] f32 {0,1}
    const float* a = (const float*)d_in[1];   // [100, 10000]  f32 {0,1}
    float* out = (float*)d_out;               // [4096, 100]   f32

    // ws: apT2 (128,000 B) at 0; partial (2*409600*4 = 3,276,800 B) at 1 MiB
    ulonglong2* apT2 = (ulonglong2*)d_ws;
    int*        part = (int*)((char*)d_ws + (1u << 20));

    pack_a_t<<<25, 256, 0, stream>>>(a, apT2);
    fused_v6<<<2048, 256, 0, stream>>>(q, apT2, part);
    combine_v6<<<OUTN / 256, 256, 0, stream>>>(part, out);
}